// Round 16
// baseline (576.191 us; speedup 1.0000x reference)
//
#include <hip/hip_runtime.h>

typedef __attribute__((ext_vector_type(8))) short s16x8;
typedef __attribute__((ext_vector_type(4))) float f32x4;
typedef __attribute__((ext_vector_type(4))) int i32x4;

#define NMID 782
#define PI_2 1.5707963267948966f
#define EG_STEP_BYTES 16384  // [16 frag][64 lane][16B]
#define EG_ELEMS ((size_t)NMID * 8192)

__device__ __forceinline__ int cvt_pk_bf16(float a, float b) {
  int r;
  asm("v_cvt_pk_bf16_f32 %0, %1, %2" : "=v"(r) : "v"(a), "v"(b));
  return r;
}

__device__ __forceinline__ f32x4 mfma_bf16(i32x4 a, i32x4 b, f32x4 c) {
  return __builtin_amdgcn_mfma_f32_16x16x32_bf16(
      __builtin_bit_cast(s16x8, a), __builtin_bit_cast(s16x8, b), c, 0, 0, 0);
}

__device__ __forceinline__ unsigned short bf16_rne(float v) {
  unsigned u = __float_as_uint(v);
  return (unsigned short)((u + 0x7FFFu + ((u >> 16) & 1)) >> 16);
}

// ---- prep: cm [782][2][64][64] f32 -> EG [782][16][64][8] bf16, E = cm - I,
// rows permuted by pi and laid out fragment-linear for direct b128 loads.
// EG[n][q=t*4+cc][l][e] = cm[n][f][i][j] - (i==j), where f=cc>>1, h=l>>4,
//   i = 32*(cc&1) + 16*(e>>2) + 4*h + (e&3),  j = 16*t + (l&15).
__global__ __launch_bounds__(256) void prep_eg(const float* __restrict__ cm,
                                               unsigned short* __restrict__ eg) {
  const int n = blockIdx.x;
  const float* src = cm + (size_t)n * 8192;
  unsigned short* dst = eg + (size_t)n * 8192;
#pragma unroll
  for (int it = 0; it < 4; ++it) {
    int row = it * 256 + threadIdx.x;  // [0,1024): (t*4+cc)*64 + l
    int q = row >> 6, l = row & 63;
    int t = q >> 2, cc = q & 3;
    int f = cc >> 1, c2 = cc & 1, h = l >> 4;
    int j = 16 * t + (l & 15);
    unsigned short v8[8];
#pragma unroll
    for (int e = 0; e < 8; ++e) {
      int i = 32 * c2 + 16 * (e >> 2) + 4 * h + (e & 3);
      float val = src[(f * 64 + i) * 64 + j] - (i == j ? 1.0f : 0.0f);
      v8[e] = bf16_rne(val);
    }
    *(uint4*)(dst + (size_t)row * 8) = *(const uint4*)v8;
  }
}

// One chain step, ONE wave computing TWO full 16-row chains (no exchange,
// no LDS, no barrier on the M recurrence). A-frags (CUR) shared by both
// chains; prefetch tile nc+1 -> NXT; B repacked in-register at step end.
#define STEP2C(nc, CUR, NXT, X0v, X1v, RS0, RS1)                            \
  {                                                                         \
    int np = (nc) + 1;                                                      \
    if (np >= NMID) np = NMID - 1;                                          \
    const char* pnxt = base + (size_t)np * EG_STEP_BYTES;                   \
    _Pragma("unroll") for (int q = 0; q < 16; ++q)                          \
        NXT[q] = *(const i32x4*)(pnxt + q * 1024);                          \
    float c0, s0, c1, s1;                                                   \
    __sincosf(PI_2 * (X0v), &s0, &c0);                                      \
    __sincosf(PI_2 * (X1v), &s1, &c1);                                      \
    c0 *= (RS0);                                                            \
    s0 *= (RS0);                                                            \
    c1 *= (RS1);                                                            \
    s1 *= (RS1);                                                            \
    float cps0 = c0 + s0, cps1 = c1 + s1;                                   \
    f32x4 z = {0.f, 0.f, 0.f, 0.f};                                         \
    _Pragma("unroll") for (int t = 0; t < 4; ++t) {                         \
      __builtin_amdgcn_s_setprio(1);                                        \
      f32x4 aA0 = mfma_bf16(CUR[4 * t + 0], B0a, z);                        \
      aA0 = mfma_bf16(CUR[4 * t + 1], B1a, aA0);                            \
      f32x4 aB0 = mfma_bf16(CUR[4 * t + 2], B0a, z);                        \
      aB0 = mfma_bf16(CUR[4 * t + 3], B1a, aB0);                            \
      f32x4 aA1 = mfma_bf16(CUR[4 * t + 0], B0b, z);                        \
      aA1 = mfma_bf16(CUR[4 * t + 1], B1b, aA1);                            \
      f32x4 aB1 = mfma_bf16(CUR[4 * t + 2], B0b, z);                        \
      aB1 = mfma_bf16(CUR[4 * t + 3], B1b, aB1);                            \
      __builtin_amdgcn_s_setprio(0);                                        \
      _Pragma("unroll") for (int r = 0; r < 4; ++r) {                       \
        m0[4 * t + r] = cps0 * m0[4 * t + r] + c0 * aA0[r] + s0 * aB0[r];   \
        m1[4 * t + r] = cps1 * m1[4 * t + r] + c1 * aA1[r] + s1 * aB1[r];   \
      }                                                                     \
    }                                                                       \
    _Pragma("unroll") for (int p = 0; p < 4; ++p) {                         \
      B0a[p] = cvt_pk_bf16(m0[2 * p], m0[2 * p + 1]);                       \
      B1a[p] = cvt_pk_bf16(m0[8 + 2 * p], m0[8 + 2 * p + 1]);               \
      B0b[p] = cvt_pk_bf16(m1[2 * p], m1[2 * p + 1]);                       \
      B1b[p] = cvt_pk_bf16(m1[8 + 2 * p], m1[8 + 2 * p + 1]);               \
    }                                                                       \
  }

// ---- main: 256 blocks x 64 threads (1 wave). Wave owns 32 batch rows as
// two independent full-M chains; M recurrence is register-only (critical
// path: MFMA pair + FMA update + cvt_pk -- no LDS, no barriers).
__global__ __launch_bounds__(64) void mps_main(
    const float* __restrict__ x, const float* __restrict__ core0,
    const float* __restrict__ core_last, const unsigned short* __restrict__ eg,
    float* __restrict__ out) {
  const int lane = threadIdx.x;
  const int bl = lane & 15;
  const int h = lane >> 4;
  const int b0 = blockIdx.x * 32 + bl;
  const int b1 = b0 + 16;
  const float* xr0 = x + (size_t)b0 * 784;
  const float* xr1 = x + (size_t)b1 * 784;
  const char* base = (const char*)eg + (size_t)lane * 16;

  float m0[16], m1[16];
  i32x4 B0a, B1a, B0b, B1b;
  {
    float s, c;
    __sincosf(PI_2 * xr0[0], &s, &c);
#pragma unroll
    for (int t = 0; t < 4; ++t)
#pragma unroll
      for (int r = 0; r < 4; ++r) {
        int j = 16 * t + 4 * h + r;
        m0[t * 4 + r] = c * core0[j] + s * core0[64 + j];
      }
    __sincosf(PI_2 * xr1[0], &s, &c);
#pragma unroll
    for (int t = 0; t < 4; ++t)
#pragma unroll
      for (int r = 0; r < 4; ++r) {
        int j = 16 * t + 4 * h + r;
        m1[t * 4 + r] = c * core0[j] + s * core0[64 + j];
      }
#pragma unroll
    for (int p = 0; p < 4; ++p) {
      B0a[p] = cvt_pk_bf16(m0[2 * p], m0[2 * p + 1]);
      B1a[p] = cvt_pk_bf16(m0[8 + 2 * p], m0[8 + 2 * p + 1]);
      B0b[p] = cvt_pk_bf16(m1[2 * p], m1[2 * p + 1]);
      B1b[p] = cvt_pk_bf16(m1[8 + 2 * p], m1[8 + 2 * p + 1]);
    }
  }

  // prologue: tile 0 -> frA
  i32x4 frA[16], frB[16];
#pragma unroll
  for (int q = 0; q < 16; ++q) frA[q] = *(const i32x4*)(base + q * 1024);

  // rolling x windows: xq covers x[8g .. 8g+11] per chain; 2 in-flight quads
  float xq0[12], xq1[12];
  f32x4 xfA0, xfB0, xfA1, xfB1;
  *(f32x4*)&xq0[0] = *(const f32x4*)(xr0 + 0);
  *(f32x4*)&xq0[4] = *(const f32x4*)(xr0 + 4);
  *(f32x4*)&xq0[8] = *(const f32x4*)(xr0 + 8);
  *(f32x4*)&xq1[0] = *(const f32x4*)(xr1 + 0);
  *(f32x4*)&xq1[4] = *(const f32x4*)(xr1 + 4);
  *(f32x4*)&xq1[8] = *(const f32x4*)(xr1 + 8);

  // 97 groups of 8 steps (n = 0..775); frag rotation period 2 | 8
  for (int g = 0; g < 97; ++g) {
    if (g > 0) {  // consume quads issued during group g-1
#pragma unroll
      for (int i = 0; i < 4; ++i) {
        xq0[i] = xq0[8 + i];
        xq1[i] = xq1[8 + i];
      }
      *(f32x4*)&xq0[4] = xfA0;
      *(f32x4*)&xq0[8] = xfB0;
      *(f32x4*)&xq1[4] = xfA1;
      *(f32x4*)&xq1[8] = xfB1;
    }
    // issue next group's quads BEFORE this group's frag loads (in-order
    // vmcnt: their wait never drains the frag queue)
    {
      int xo = (g < 96) ? 8 * g + 12 : 780;
      int xo2 = (g < 96) ? 8 * g + 16 : 780;  // g=96: dup-guard (no OOB)
      xfA0 = *(const f32x4*)(xr0 + xo);
      xfB0 = *(const f32x4*)(xr0 + xo2);
      xfA1 = *(const f32x4*)(xr1 + xo);
      xfB1 = *(const f32x4*)(xr1 + xo2);
    }

    float rs0 = 1.0f, rs1 = 1.0f;
    if ((g & 7) == 0) {  // rescale every 64 steps, folded into step-0 scalars
      float ss0 = 0.f, ss1 = 0.f;
#pragma unroll
      for (int i = 0; i < 16; ++i) {
        ss0 += m0[i] * m0[i];
        ss1 += m1[i] * m1[i];
      }
      ss0 += __shfl_xor(ss0, 16);
      ss0 += __shfl_xor(ss0, 32);
      ss1 += __shfl_xor(ss1, 16);
      ss1 += __shfl_xor(ss1, 32);
      rs0 = rsqrtf(ss0);
      rs1 = rsqrtf(ss1);
    }

    int n0 = 8 * g;  // n0 % 2 == 0
    STEP2C(n0 + 0, frA, frB, xq0[1], xq1[1], rs0, rs1);
    STEP2C(n0 + 1, frB, frA, xq0[2], xq1[2], 1.0f, 1.0f);
    STEP2C(n0 + 2, frA, frB, xq0[3], xq1[3], 1.0f, 1.0f);
    STEP2C(n0 + 3, frB, frA, xq0[4], xq1[4], 1.0f, 1.0f);
    STEP2C(n0 + 4, frA, frB, xq0[5], xq1[5], 1.0f, 1.0f);
    STEP2C(n0 + 5, frB, frA, xq0[6], xq1[6], 1.0f, 1.0f);
    STEP2C(n0 + 6, frA, frB, xq0[7], xq1[7], 1.0f, 1.0f);
    STEP2C(n0 + 7, frB, frA, xq0[8], xq1[8], 1.0f, 1.0f);
  }

  // tail: shift once more (xf from g=96 = quad 780); steps 776..781
  {
#pragma unroll
    for (int i = 0; i < 4; ++i) {
      xq0[i] = xq0[8 + i];
      xq1[i] = xq1[8 + i];
    }
    *(f32x4*)&xq0[4] = xfA0;
    *(f32x4*)&xq1[4] = xfA1;
    STEP2C(776, frA, frB, xq0[1], xq1[1], 1.0f, 1.0f);
    STEP2C(777, frB, frA, xq0[2], xq1[2], 1.0f, 1.0f);
    STEP2C(778, frA, frB, xq0[3], xq1[3], 1.0f, 1.0f);
    STEP2C(779, frB, frA, xq0[4], xq1[4], 1.0f, 1.0f);
    STEP2C(780, frA, frB, xq0[5], xq1[5], 1.0f, 1.0f);
    STEP2C(781, frB, frA, xq0[6], xq1[6], 1.0f, 1.0f);
  }

  // epilogue per chain: normalize + logits (no LDS needed -- m is full M)
#pragma unroll
  for (int grp = 0; grp < 2; ++grp) {
    float fm[16];
#pragma unroll
    for (int i = 0; i < 16; ++i) fm[i] = grp == 0 ? m0[i] : m1[i];
    float ss = 0.f;
#pragma unroll
    for (int i = 0; i < 16; ++i) ss += fm[i] * fm[i];
    ss += __shfl_xor(ss, 16);
    ss += __shfl_xor(ss, 32);
    float inv = 1.0f / (sqrtf(ss) + 1e-8f);
#pragma unroll
    for (int i = 0; i < 16; ++i) fm[i] *= inv;

    float xv = grp == 0 ? xq0[7] : xq1[7];  // x[783]
    float s, c;
    __sincosf(PI_2 * xv, &s, &c);
    float part[10];
#pragma unroll
    for (int cc = 0; cc < 10; ++cc) part[cc] = 0.f;
#pragma unroll
    for (int t = 0; t < 4; ++t)
#pragma unroll
      for (int r = 0; r < 4; ++r) {
        int i = 16 * t + 4 * h + r;
        float mv = fm[t * 4 + r];
#pragma unroll
        for (int cc = 0; cc < 10; ++cc)
          part[cc] +=
              mv * (c * core_last[i * 10 + cc] + s * core_last[640 + i * 10 + cc]);
      }
#pragma unroll
    for (int cc = 0; cc < 10; ++cc) {
      part[cc] += __shfl_xor(part[cc], 16);
      part[cc] += __shfl_xor(part[cc], 32);
    }
    if (h == 0) {
      int brow = grp == 0 ? b0 : b1;
#pragma unroll
      for (int cc = 0; cc < 10; ++cc) out[brow * 10 + cc] = part[cc];
    }
  }
}

// ---- fallback (only if d_ws too small): slow but correct scalar path
__global__ __launch_bounds__(64) void mps_slow(const float* __restrict__ x,
                                               const float* __restrict__ core0,
                                               const float* __restrict__ cm,
                                               const float* __restrict__ cl,
                                               float* __restrict__ out) {
  int b = blockIdx.x * 64 + threadIdx.x;
  float m[64], mn[64];
  float s, c;
  __sincosf(PI_2 * x[(size_t)b * 784], &s, &c);
  for (int d = 0; d < 64; ++d) m[d] = c * core0[d] + s * core0[64 + d];
  for (int n = 0; n < NMID; ++n) {
    __sincosf(PI_2 * x[(size_t)b * 784 + n + 1], &s, &c);
    const float* A0 = cm + (size_t)n * 8192;
    const float* A1 = A0 + 4096;
    for (int j = 0; j < 64; ++j) mn[j] = 0.f;
    for (int i = 0; i < 64; ++i) {
      float w0 = c * m[i], w1 = s * m[i];
      for (int j = 0; j < 64; ++j) mn[j] += w0 * A0[i * 64 + j] + w1 * A1[i * 64 + j];
    }
    float ssn = 0.f;
    for (int j = 0; j < 64; ++j) ssn += mn[j] * mn[j];
    float inv = 1.f / (sqrtf(ssn) + 1e-8f);
    for (int j = 0; j < 64; ++j) m[j] = mn[j] * inv;
  }
  __sincosf(PI_2 * x[(size_t)b * 784 + 783], &s, &c);
  for (int cc = 0; cc < 10; ++cc) {
    float acc = 0.f;
    for (int i = 0; i < 64; ++i)
      acc += m[i] * (c * cl[i * 10 + cc] + s * cl[640 + i * 10 + cc]);
    out[b * 10 + cc] = acc;
  }
}

extern "C" void kernel_launch(void* const* d_in, const int* in_sizes, int n_in,
                              void* d_out, int out_size, void* d_ws, size_t ws_size,
                              hipStream_t stream) {
  const float* x = (const float*)d_in[0];
  const float* core0 = (const float*)d_in[1];
  const float* cm = (const float*)d_in[2];
  const float* cl = (const float*)d_in[3];
  float* out = (float*)d_out;
  size_t need = EG_ELEMS * sizeof(unsigned short);
  if (ws_size >= need) {
    unsigned short* eg = (unsigned short*)d_ws;
    prep_eg<<<NMID, 256, 0, stream>>>(cm, eg);
    mps_main<<<256, 64, 0, stream>>>(x, core0, cl, eg, out);
  } else {
    mps_slow<<<8192 / 64, 64, 0, stream>>>(x, core0, cm, cl, out);
  }
}

// Round 17
// 284.360 us; speedup vs baseline: 2.0263x; 2.0263x over previous
//
#include <hip/hip_runtime.h>

typedef __attribute__((ext_vector_type(8))) short s16x8;
typedef __attribute__((ext_vector_type(4))) float f32x4;
typedef __attribute__((ext_vector_type(4))) int i32x4;

#define NMID 782
#define PI_2 1.5707963267948966f
#define EG_STEP_BYTES 16384  // [16 frag][64 lane][16B]
#define EG_ELEMS ((size_t)NMID * 8192)
#define XCH_CH 3072   // per-chain exchange slab per parity: [h 4][bl 16][48B]
#define XCH_PAR 6144  // both chains, one parity

__device__ __forceinline__ int cvt_pk_bf16(float a, float b) {
  int r;
  asm("v_cvt_pk_bf16_f32 %0, %1, %2" : "=v"(r) : "v"(a), "v"(b));
  return r;
}

__device__ __forceinline__ f32x4 mfma_bf16(i32x4 a, i32x4 b, f32x4 c) {
  return __builtin_amdgcn_mfma_f32_16x16x32_bf16(
      __builtin_bit_cast(s16x8, a), __builtin_bit_cast(s16x8, b), c, 0, 0, 0);
}

__device__ __forceinline__ unsigned short bf16_rne(float v) {
  unsigned u = __float_as_uint(v);
  return (unsigned short)((u + 0x7FFFu + ((u >> 16) & 1)) >> 16);
}

// ---- prep: cm [782][2][64][64] f32 -> EG [782][16][64][8] bf16, E = cm - I,
// rows permuted by pi and laid out fragment-linear for direct b128 loads.
// EG[n][q=t*4+cc][l][e] = cm[n][f][i][j] - (i==j), where f=cc>>1, h=l>>4,
//   i = 32*(cc&1) + 16*(e>>2) + 4*h + (e&3),  j = 16*t + (l&15).
__global__ __launch_bounds__(256) void prep_eg(const float* __restrict__ cm,
                                               unsigned short* __restrict__ eg) {
  const int n = blockIdx.x;
  const float* src = cm + (size_t)n * 8192;
  unsigned short* dst = eg + (size_t)n * 8192;
#pragma unroll
  for (int it = 0; it < 4; ++it) {
    int row = it * 256 + threadIdx.x;  // [0,1024): (t*4+cc)*64 + l
    int q = row >> 6, l = row & 63;
    int t = q >> 2, cc = q & 3;
    int f = cc >> 1, c2 = cc & 1, h = l >> 4;
    int j = 16 * t + (l & 15);
    unsigned short v8[8];
#pragma unroll
    for (int e = 0; e < 8; ++e) {
      int i = 32 * c2 + 16 * (e >> 2) + 4 * h + (e & 3);
      float val = src[(f * 64 + i) * 64 + j] - (i == j ? 1.0f : 0.0f);
      v8[e] = bf16_rne(val);
    }
    *(uint4*)(dst + (size_t)row * 8) = *(const uint4*)v8;
  }
}

// One chain step, 4-wave j-split x TWO independent 16-row chains sharing the
// same E fragments. Sincos computed inline (off the critical path); RS folds
// the periodic rescale into step scalars. One raw s_barrier; vmcnt never
// drained. Exchange slab: h-plane layout, 48B rows (2-way reads = free).
#define STEP2G(nc, CUR, NXT, X0v, X1v, RS0, RS1)                            \
  {                                                                         \
    int np = (nc) + 3;                                                      \
    if (np >= NMID) np = NMID - 1;                                          \
    const char* pnxt = base + (size_t)np * EG_STEP_BYTES;                   \
    _Pragma("unroll") for (int q = 0; q < 4; ++q)                           \
        NXT[q] = *(const i32x4*)(pnxt + q * 1024);                          \
    float c0, s0, c1, s1;                                                   \
    __sincosf(PI_2 * (X0v), &s0, &c0);                                      \
    __sincosf(PI_2 * (X1v), &s1, &c1);                                      \
    c0 *= (RS0);                                                            \
    s0 *= (RS0);                                                            \
    c1 *= (RS1);                                                            \
    s1 *= (RS1);                                                            \
    f32x4 z = {0.f, 0.f, 0.f, 0.f};                                         \
    __builtin_amdgcn_s_setprio(1);                                          \
    f32x4 aA0 = mfma_bf16(CUR[0], B0g0, z);                                 \
    aA0 = mfma_bf16(CUR[1], B1g0, aA0);                                     \
    f32x4 aB0 = mfma_bf16(CUR[2], B0g0, z);                                 \
    aB0 = mfma_bf16(CUR[3], B1g0, aB0);                                     \
    f32x4 aA1 = mfma_bf16(CUR[0], B0g1, z);                                 \
    aA1 = mfma_bf16(CUR[1], B1g1, aA1);                                     \
    f32x4 aB1 = mfma_bf16(CUR[2], B0g1, z);                                 \
    aB1 = mfma_bf16(CUR[3], B1g1, aB1);                                     \
    __builtin_amdgcn_s_setprio(0);                                          \
    char* wb = xlds + (((nc) + 1) & 1) * XCH_PAR + h * 768 + bl * 48 +      \
               wv * 8;                                                      \
    float cps0 = c0 + s0;                                                   \
    f32x4 mn0;                                                              \
    _Pragma("unroll") for (int r = 0; r < 4; ++r)                           \
        mn0[r] = cps0 * own0[r] + c0 * aA0[r] + s0 * aB0[r];                \
    own0 = mn0;                                                             \
    int2 w0;                                                                \
    w0.x = cvt_pk_bf16(mn0[0], mn0[1]);                                     \
    w0.y = cvt_pk_bf16(mn0[2], mn0[3]);                                     \
    *(int2*)(wb) = w0;                                                      \
    float cps1 = c1 + s1;                                                   \
    f32x4 mn1;                                                              \
    _Pragma("unroll") for (int r = 0; r < 4; ++r)                           \
        mn1[r] = cps1 * own1[r] + c1 * aA1[r] + s1 * aB1[r];                \
    own1 = mn1;                                                             \
    int2 w1;                                                                \
    w1.x = cvt_pk_bf16(mn1[0], mn1[1]);                                     \
    w1.y = cvt_pk_bf16(mn1[2], mn1[3]);                                     \
    *(int2*)(wb + XCH_CH) = w1;                                             \
    asm volatile("s_waitcnt lgkmcnt(0)" ::: "memory");                      \
    __builtin_amdgcn_s_barrier();                                           \
    __builtin_amdgcn_sched_barrier(0);                                      \
    {                                                                       \
      const char* rb =                                                      \
          xlds + (((nc) + 1) & 1) * XCH_PAR + h * 768 + bl * 48;            \
      B0g0 = *(const i32x4*)(rb);                                           \
      B1g0 = *(const i32x4*)(rb + 16);                                      \
      B0g1 = *(const i32x4*)(rb + XCH_CH);                                  \
      B1g1 = *(const i32x4*)(rb + XCH_CH + 16);                             \
    }                                                                       \
  }

// ---- main: 256 blocks x 256 threads. Block owns 32 batch rows = two
// independent 16-row chains; wave wv owns j-tile [16wv,16wv+16) for BOTH
// chains with the SAME E-fragment registers. (256,1): grid is 1 block/CU,
// so do not cap VGPRs for an occupancy the grid can never reach.
__global__ __launch_bounds__(256, 1) void mps_main(
    const float* __restrict__ x, const float* __restrict__ core0,
    const float* __restrict__ core_last, const unsigned short* __restrict__ eg,
    float* __restrict__ out) {
  __shared__ alignas(16) char xlds[2 * XCH_PAR];
  const int lane = threadIdx.x & 63;
  const int wv = threadIdx.x >> 6;
  const int bl = lane & 15;
  const int h = lane >> 4;
  const int b0 = blockIdx.x * 32 + bl;
  const int b1 = b0 + 16;
  const float* xr0 = x + (size_t)b0 * 784;
  const float* xr1 = x + (size_t)b1 * 784;
  const char* base = (const char*)eg + (size_t)wv * 4096 + (size_t)lane * 16;

  f32x4 own0, own1;
  i32x4 B0g0, B1g0, B0g1, B1g1;
  {
    float s, c;
    __sincosf(PI_2 * xr0[0], &s, &c);
    float fm[16];
#pragma unroll
    for (int t = 0; t < 4; ++t)
#pragma unroll
      for (int r = 0; r < 4; ++r) {
        int j = 16 * t + 4 * h + r;
        fm[t * 4 + r] = c * core0[j] + s * core0[64 + j];
      }
#pragma unroll
    for (int r = 0; r < 4; ++r) own0[r] = fm[wv * 4 + r];
#pragma unroll
    for (int p = 0; p < 4; ++p) {
      B0g0[p] = cvt_pk_bf16(fm[2 * p], fm[2 * p + 1]);
      B1g0[p] = cvt_pk_bf16(fm[8 + 2 * p], fm[8 + 2 * p + 1]);
    }
  }
  {
    float s, c;
    __sincosf(PI_2 * xr1[0], &s, &c);
    float fm[16];
#pragma unroll
    for (int t = 0; t < 4; ++t)
#pragma unroll
      for (int r = 0; r < 4; ++r) {
        int j = 16 * t + 4 * h + r;
        fm[t * 4 + r] = c * core0[j] + s * core0[64 + j];
      }
#pragma unroll
    for (int r = 0; r < 4; ++r) own1[r] = fm[wv * 4 + r];
#pragma unroll
    for (int p = 0; p < 4; ++p) {
      B0g1[p] = cvt_pk_bf16(fm[2 * p], fm[2 * p + 1]);
      B1g1[p] = cvt_pk_bf16(fm[8 + 2 * p], fm[8 + 2 * p + 1]);
    }
  }

  // prologue: own-tile frags for steps 0,1,2 -> A,B,C (shared by both chains)
  i32x4 frA[4], frB[4], frC[4], frD[4];
#pragma unroll
  for (int q = 0; q < 4; ++q)
    frA[q] = *(const i32x4*)(base + 0 * EG_STEP_BYTES + q * 1024);
#pragma unroll
  for (int q = 0; q < 4; ++q)
    frB[q] = *(const i32x4*)(base + 1 * EG_STEP_BYTES + q * 1024);
#pragma unroll
  for (int q = 0; q < 4; ++q)
    frC[q] = *(const i32x4*)(base + 2 * EG_STEP_BYTES + q * 1024);

  // rolling x windows: xq covers x[8g .. 8g+11]; xf = 2 in-flight quads/chain
  float xq0[12], xq1[12];
  f32x4 xfA0, xfB0, xfA1, xfB1;
  *(f32x4*)&xq0[0] = *(const f32x4*)(xr0 + 0);
  *(f32x4*)&xq0[4] = *(const f32x4*)(xr0 + 4);
  *(f32x4*)&xq0[8] = *(const f32x4*)(xr0 + 8);
  *(f32x4*)&xq1[0] = *(const f32x4*)(xr1 + 0);
  *(f32x4*)&xq1[4] = *(const f32x4*)(xr1 + 4);
  *(f32x4*)&xq1[8] = *(const f32x4*)(xr1 + 8);

  // 97 groups of 8 steps (n = 0..775); frag rotation period 4 | 8
  for (int g = 0; g < 97; ++g) {
    if (g > 0) {  // consume quads issued during group g-1
#pragma unroll
      for (int i = 0; i < 4; ++i) {
        xq0[i] = xq0[8 + i];
        xq1[i] = xq1[8 + i];
      }
      *(f32x4*)&xq0[4] = xfA0;
      *(f32x4*)&xq0[8] = xfB0;
      *(f32x4*)&xq1[4] = xfA1;
      *(f32x4*)&xq1[8] = xfB1;
    }
    // issue next group's quads BEFORE this group's frag loads (in-order
    // vmcnt: their wait never drains the frag queue)
    {
      int xo = (g < 96) ? 8 * g + 12 : 780;
      int xo2 = (g < 96) ? 8 * g + 16 : 780;  // g=96: dup-guard (no OOB)
      xfA0 = *(const f32x4*)(xr0 + xo);
      xfB0 = *(const f32x4*)(xr0 + xo2);
      xfA1 = *(const f32x4*)(xr1 + xo);
      xfB1 = *(const f32x4*)(xr1 + xo2);
    }

    float rs0 = 1.0f, rs1 = 1.0f;
    if ((g & 7) == 0) {  // rescale every 64 steps, folded into step-0 scalars
      float ss0 = 0.f, ss1 = 0.f;
#pragma unroll
      for (int p = 0; p < 4; ++p) {
        unsigned u0 = (unsigned)B0g0[p], u1 = (unsigned)B1g0[p];
        float a0 = __uint_as_float(u0 << 16);
        float a1 = __uint_as_float(u0 & 0xFFFF0000u);
        float d0 = __uint_as_float(u1 << 16);
        float d1 = __uint_as_float(u1 & 0xFFFF0000u);
        ss0 += a0 * a0 + a1 * a1 + d0 * d0 + d1 * d1;
        unsigned v0 = (unsigned)B0g1[p], v1 = (unsigned)B1g1[p];
        float e0 = __uint_as_float(v0 << 16);
        float e1 = __uint_as_float(v0 & 0xFFFF0000u);
        float f0 = __uint_as_float(v1 << 16);
        float f1 = __uint_as_float(v1 & 0xFFFF0000u);
        ss1 += e0 * e0 + e1 * e1 + f0 * f0 + f1 * f1;
      }
      ss0 += __shfl_xor(ss0, 16);
      ss0 += __shfl_xor(ss0, 32);
      ss1 += __shfl_xor(ss1, 16);
      ss1 += __shfl_xor(ss1, 32);
      rs0 = rsqrtf(ss0);
      rs1 = rsqrtf(ss1);
    }

    int n0 = 8 * g;  // n0 % 4 == 0
    STEP2G(n0 + 0, frA, frD, xq0[1], xq1[1], rs0, rs1);
    STEP2G(n0 + 1, frB, frA, xq0[2], xq1[2], 1.0f, 1.0f);
    STEP2G(n0 + 2, frC, frB, xq0[3], xq1[3], 1.0f, 1.0f);
    STEP2G(n0 + 3, frD, frC, xq0[4], xq1[4], 1.0f, 1.0f);
    STEP2G(n0 + 4, frA, frD, xq0[5], xq1[5], 1.0f, 1.0f);
    STEP2G(n0 + 5, frB, frA, xq0[6], xq1[6], 1.0f, 1.0f);
    STEP2G(n0 + 6, frC, frB, xq0[7], xq1[7], 1.0f, 1.0f);
    STEP2G(n0 + 7, frD, frC, xq0[8], xq1[8], 1.0f, 1.0f);
  }

  // tail: shift once more (xf from g=96 = quad 780); steps 776..781
  {
#pragma unroll
    for (int i = 0; i < 4; ++i) {
      xq0[i] = xq0[8 + i];
      xq1[i] = xq1[8 + i];
    }
    *(f32x4*)&xq0[4] = xfA0;
    *(f32x4*)&xq1[4] = xfA1;
    STEP2G(776, frA, frD, xq0[1], xq1[1], 1.0f, 1.0f);
    STEP2G(777, frB, frA, xq0[2], xq1[2], 1.0f, 1.0f);
    STEP2G(778, frC, frB, xq0[3], xq1[3], 1.0f, 1.0f);
    STEP2G(779, frD, frC, xq0[4], xq1[4], 1.0f, 1.0f);
    STEP2G(780, frA, frD, xq0[5], xq1[5], 1.0f, 1.0f);
    STEP2G(781, frB, frA, xq0[6], xq1[6], 1.0f, 1.0f);
  }

  // final f32 exchange (unique per (wv,lane)); then normalize + logits, x2
  asm volatile("s_waitcnt lgkmcnt(0)" ::: "memory");
  __builtin_amdgcn_s_barrier();  // all step reads retired
  *(f32x4*)(xlds + wv * 1152 + lane * 16) = own0;
  *(f32x4*)(xlds + 4608 + wv * 1152 + lane * 16) = own1;
  asm volatile("s_waitcnt lgkmcnt(0)" ::: "memory");
  __builtin_amdgcn_s_barrier();
  __builtin_amdgcn_sched_barrier(0);

#pragma unroll
  for (int grp = 0; grp < 2; ++grp) {
    float fm[16];
#pragma unroll
    for (int t = 0; t < 4; ++t) {
      f32x4 v = *(const f32x4*)(xlds + grp * 4608 + t * 1152 + lane * 16);
#pragma unroll
      for (int r = 0; r < 4; ++r) fm[t * 4 + r] = v[r];
    }
    float ss = 0.f;
#pragma unroll
    for (int i = 0; i < 16; ++i) ss += fm[i] * fm[i];
    ss += __shfl_xor(ss, 16);
    ss += __shfl_xor(ss, 32);
    float inv = 1.0f / (sqrtf(ss) + 1e-8f);
#pragma unroll
    for (int i = 0; i < 16; ++i) fm[i] *= inv;

    float xv = grp == 0 ? xq0[7] : xq1[7];  // x[783]
    float s, c;
    __sincosf(PI_2 * xv, &s, &c);
    float part[10];
#pragma unroll
    for (int cc = 0; cc < 10; ++cc) part[cc] = 0.f;
#pragma unroll
    for (int t = 0; t < 4; ++t)
#pragma unroll
      for (int r = 0; r < 4; ++r) {
        int i = 16 * t + 4 * h + r;
        float mv = fm[t * 4 + r];
#pragma unroll
        for (int cc = 0; cc < 10; ++cc)
          part[cc] +=
              mv * (c * core_last[i * 10 + cc] + s * core_last[640 + i * 10 + cc]);
      }
#pragma unroll
    for (int cc = 0; cc < 10; ++cc) {
      part[cc] += __shfl_xor(part[cc], 16);
      part[cc] += __shfl_xor(part[cc], 32);
    }
    if (wv == 0 && h == 0) {
      int brow = grp == 0 ? b0 : b1;
#pragma unroll
      for (int cc = 0; cc < 10; ++cc) out[brow * 10 + cc] = part[cc];
    }
  }
}

// ---- fallback (only if d_ws too small): slow but correct scalar path
__global__ __launch_bounds__(64) void mps_slow(const float* __restrict__ x,
                                               const float* __restrict__ core0,
                                               const float* __restrict__ cm,
                                               const float* __restrict__ cl,
                                               float* __restrict__ out) {
  int b = blockIdx.x * 64 + threadIdx.x;
  float m[64], mn[64];
  float s, c;
  __sincosf(PI_2 * x[(size_t)b * 784], &s, &c);
  for (int d = 0; d < 64; ++d) m[d] = c * core0[d] + s * core0[64 + d];
  for (int n = 0; n < NMID; ++n) {
    __sincosf(PI_2 * x[(size_t)b * 784 + n + 1], &s, &c);
    const float* A0 = cm + (size_t)n * 8192;
    const float* A1 = A0 + 4096;
    for (int j = 0; j < 64; ++j) mn[j] = 0.f;
    for (int i = 0; i < 64; ++i) {
      float w0 = c * m[i], w1 = s * m[i];
      for (int j = 0; j < 64; ++j) mn[j] += w0 * A0[i * 64 + j] + w1 * A1[i * 64 + j];
    }
    float ssn = 0.f;
    for (int j = 0; j < 64; ++j) ssn += mn[j] * mn[j];
    float inv = 1.f / (sqrtf(ssn) + 1e-8f);
    for (int j = 0; j < 64; ++j) m[j] = mn[j] * inv;
  }
  __sincosf(PI_2 * x[(size_t)b * 784 + 783], &s, &c);
  for (int cc = 0; cc < 10; ++cc) {
    float acc = 0.f;
    for (int i = 0; i < 64; ++i)
      acc += m[i] * (c * cl[i * 10 + cc] + s * cl[640 + i * 10 + cc]);
    out[b * 10 + cc] = acc;
  }
}

extern "C" void kernel_launch(void* const* d_in, const int* in_sizes, int n_in,
                              void* d_out, int out_size, void* d_ws, size_t ws_size,
                              hipStream_t stream) {
  const float* x = (const float*)d_in[0];
  const float* core0 = (const float*)d_in[1];
  const float* cm = (const float*)d_in[2];
  const float* cl = (const float*)d_in[3];
  float* out = (float*)d_out;
  size_t need = EG_ELEMS * sizeof(unsigned short);
  if (ws_size >= need) {
    unsigned short* eg = (unsigned short*)d_ws;
    prep_eg<<<NMID, 256, 0, stream>>>(cm, eg);
    mps_main<<<256, 256, 0, stream>>>(x, core0, cl, eg, out);
  } else {
    mps_slow<<<8192 / 64, 64, 0, stream>>>(x, core0, cm, cl, out);
  }
}

// Round 18
// 245.663 us; speedup vs baseline: 2.3455x; 1.1575x over previous
//
#include <hip/hip_runtime.h>

typedef __attribute__((ext_vector_type(8))) short s16x8;
typedef __attribute__((ext_vector_type(4))) float f32x4;
typedef __attribute__((ext_vector_type(4))) int i32x4;

#define NMID 782
#define PI_2 1.5707963267948966f
#define EG_STEP_BYTES 16384  // [16 frag][64 lane][16B]
#define EG_ELEMS ((size_t)NMID * 8192)
#define XCH_CH 3072   // per-chain exchange slab per parity: [h 4][bl 16][48B]
#define XCH_PAR 6144  // both chains, one parity

__device__ __forceinline__ int cvt_pk_bf16(float a, float b) {
  int r;
  asm("v_cvt_pk_bf16_f32 %0, %1, %2" : "=v"(r) : "v"(a), "v"(b));
  return r;
}

__device__ __forceinline__ f32x4 mfma_bf16(i32x4 a, i32x4 b, f32x4 c) {
  return __builtin_amdgcn_mfma_f32_16x16x32_bf16(
      __builtin_bit_cast(s16x8, a), __builtin_bit_cast(s16x8, b), c, 0, 0, 0);
}

__device__ __forceinline__ unsigned short bf16_rne(float v) {
  unsigned u = __float_as_uint(v);
  return (unsigned short)((u + 0x7FFFu + ((u >> 16) & 1)) >> 16);
}

// ---- prep: cm [782][2][64][64] f32 -> EG [782][16][64][8] bf16, E = cm - I,
// rows permuted by pi and laid out fragment-linear for direct b128 loads.
// EG[n][q=t*4+cc][l][e] = cm[n][f][i][j] - (i==j), where f=cc>>1, h=l>>4,
//   i = 32*(cc&1) + 16*(e>>2) + 4*h + (e&3),  j = 16*t + (l&15).
__global__ __launch_bounds__(256) void prep_eg(const float* __restrict__ cm,
                                               unsigned short* __restrict__ eg) {
  const int n = blockIdx.x;
  const float* src = cm + (size_t)n * 8192;
  unsigned short* dst = eg + (size_t)n * 8192;
#pragma unroll
  for (int it = 0; it < 4; ++it) {
    int row = it * 256 + threadIdx.x;  // [0,1024): (t*4+cc)*64 + l
    int q = row >> 6, l = row & 63;
    int t = q >> 2, cc = q & 3;
    int f = cc >> 1, c2 = cc & 1, h = l >> 4;
    int j = 16 * t + (l & 15);
    unsigned short v8[8];
#pragma unroll
    for (int e = 0; e < 8; ++e) {
      int i = 32 * c2 + 16 * (e >> 2) + 4 * h + (e & 3);
      float val = src[(f * 64 + i) * 64 + j] - (i == j ? 1.0f : 0.0f);
      v8[e] = bf16_rne(val);
    }
    *(uint4*)(dst + (size_t)row * 8) = *(const uint4*)v8;
  }
}

// One chain step, 4-wave j-split x TWO independent 16-row chains sharing the
// same E fragments. Sincos computed inline (off the critical path); RS folds
// the periodic rescale into step scalars. One raw s_barrier; vmcnt never
// drained. Exchange slab: h-plane layout, 48B rows (2-way reads = free).
#define STEP2G(nc, CUR, NXT, X0v, X1v, RS0, RS1)                            \
  {                                                                         \
    int np = (nc) + 3;                                                      \
    if (np >= NMID) np = NMID - 1;                                          \
    const char* pnxt = base + (size_t)np * EG_STEP_BYTES;                   \
    _Pragma("unroll") for (int q = 0; q < 4; ++q)                           \
        NXT[q] = *(const i32x4*)(pnxt + q * 1024);                          \
    float c0, s0, c1, s1;                                                   \
    __sincosf(PI_2 * (X0v), &s0, &c0);                                      \
    __sincosf(PI_2 * (X1v), &s1, &c1);                                      \
    c0 *= (RS0);                                                            \
    s0 *= (RS0);                                                            \
    c1 *= (RS1);                                                            \
    s1 *= (RS1);                                                            \
    f32x4 z = {0.f, 0.f, 0.f, 0.f};                                         \
    __builtin_amdgcn_s_setprio(1);                                          \
    f32x4 aA0 = mfma_bf16(CUR[0], B0g0, z);                                 \
    aA0 = mfma_bf16(CUR[1], B1g0, aA0);                                     \
    f32x4 aB0 = mfma_bf16(CUR[2], B0g0, z);                                 \
    aB0 = mfma_bf16(CUR[3], B1g0, aB0);                                     \
    f32x4 aA1 = mfma_bf16(CUR[0], B0g1, z);                                 \
    aA1 = mfma_bf16(CUR[1], B1g1, aA1);                                     \
    f32x4 aB1 = mfma_bf16(CUR[2], B0g1, z);                                 \
    aB1 = mfma_bf16(CUR[3], B1g1, aB1);                                     \
    __builtin_amdgcn_s_setprio(0);                                          \
    char* wb = xlds + (((nc) + 1) & 1) * XCH_PAR + h * 768 + bl * 48 +      \
               wv * 8;                                                      \
    float cps0 = c0 + s0;                                                   \
    f32x4 mn0;                                                              \
    _Pragma("unroll") for (int r = 0; r < 4; ++r)                           \
        mn0[r] = cps0 * own0[r] + c0 * aA0[r] + s0 * aB0[r];                \
    own0 = mn0;                                                             \
    int2 w0;                                                                \
    w0.x = cvt_pk_bf16(mn0[0], mn0[1]);                                     \
    w0.y = cvt_pk_bf16(mn0[2], mn0[3]);                                     \
    *(int2*)(wb) = w0;                                                      \
    float cps1 = c1 + s1;                                                   \
    f32x4 mn1;                                                              \
    _Pragma("unroll") for (int r = 0; r < 4; ++r)                           \
        mn1[r] = cps1 * own1[r] + c1 * aA1[r] + s1 * aB1[r];                \
    own1 = mn1;                                                             \
    int2 w1;                                                                \
    w1.x = cvt_pk_bf16(mn1[0], mn1[1]);                                     \
    w1.y = cvt_pk_bf16(mn1[2], mn1[3]);                                     \
    *(int2*)(wb + XCH_CH) = w1;                                             \
    asm volatile("s_waitcnt lgkmcnt(0)" ::: "memory");                      \
    __builtin_amdgcn_s_barrier();                                           \
    __builtin_amdgcn_sched_barrier(0);                                      \
    {                                                                       \
      const char* rb =                                                      \
          xlds + (((nc) + 1) & 1) * XCH_PAR + h * 768 + bl * 48;            \
      B0g0 = *(const i32x4*)(rb);                                           \
      B1g0 = *(const i32x4*)(rb + 16);                                      \
      B0g1 = *(const i32x4*)(rb + XCH_CH);                                  \
      B1g1 = *(const i32x4*)(rb + XCH_CH + 16);                             \
    }                                                                       \
  }

// ---- main: 256 blocks x 256 threads. Block owns 32 batch rows = two
// independent 16-row chains; wave wv owns j-tile [16wv,16wv+16) for BOTH
// chains with the SAME E-fragment registers. launch_bounds (256,2): the
// 128-VGPR-capped codegen measured FASTER than (256,1) (246 vs 284us, r17
// A/B) -- tighter live ranges beat more registers at 1 wave/SIMD.
__global__ __launch_bounds__(256, 2) void mps_main(
    const float* __restrict__ x, const float* __restrict__ core0,
    const float* __restrict__ core_last, const unsigned short* __restrict__ eg,
    float* __restrict__ out) {
  __shared__ alignas(16) char xlds[2 * XCH_PAR];
  const int lane = threadIdx.x & 63;
  const int wv = threadIdx.x >> 6;
  const int bl = lane & 15;
  const int h = lane >> 4;
  const int b0 = blockIdx.x * 32 + bl;
  const int b1 = b0 + 16;
  const float* xr0 = x + (size_t)b0 * 784;
  const float* xr1 = x + (size_t)b1 * 784;
  const char* base = (const char*)eg + (size_t)wv * 4096 + (size_t)lane * 16;

  f32x4 own0, own1;
  i32x4 B0g0, B1g0, B0g1, B1g1;
  {
    float s, c;
    __sincosf(PI_2 * xr0[0], &s, &c);
    float fm[16];
#pragma unroll
    for (int t = 0; t < 4; ++t)
#pragma unroll
      for (int r = 0; r < 4; ++r) {
        int j = 16 * t + 4 * h + r;
        fm[t * 4 + r] = c * core0[j] + s * core0[64 + j];
      }
#pragma unroll
    for (int r = 0; r < 4; ++r) own0[r] = fm[wv * 4 + r];
#pragma unroll
    for (int p = 0; p < 4; ++p) {
      B0g0[p] = cvt_pk_bf16(fm[2 * p], fm[2 * p + 1]);
      B1g0[p] = cvt_pk_bf16(fm[8 + 2 * p], fm[8 + 2 * p + 1]);
    }
  }
  {
    float s, c;
    __sincosf(PI_2 * xr1[0], &s, &c);
    float fm[16];
#pragma unroll
    for (int t = 0; t < 4; ++t)
#pragma unroll
      for (int r = 0; r < 4; ++r) {
        int j = 16 * t + 4 * h + r;
        fm[t * 4 + r] = c * core0[j] + s * core0[64 + j];
      }
#pragma unroll
    for (int r = 0; r < 4; ++r) own1[r] = fm[wv * 4 + r];
#pragma unroll
    for (int p = 0; p < 4; ++p) {
      B0g1[p] = cvt_pk_bf16(fm[2 * p], fm[2 * p + 1]);
      B1g1[p] = cvt_pk_bf16(fm[8 + 2 * p], fm[8 + 2 * p + 1]);
    }
  }

  // prologue: own-tile frags for steps 0,1,2 -> A,B,C (shared by both chains)
  i32x4 frA[4], frB[4], frC[4], frD[4];
#pragma unroll
  for (int q = 0; q < 4; ++q)
    frA[q] = *(const i32x4*)(base + 0 * EG_STEP_BYTES + q * 1024);
#pragma unroll
  for (int q = 0; q < 4; ++q)
    frB[q] = *(const i32x4*)(base + 1 * EG_STEP_BYTES + q * 1024);
#pragma unroll
  for (int q = 0; q < 4; ++q)
    frC[q] = *(const i32x4*)(base + 2 * EG_STEP_BYTES + q * 1024);

  // rolling x windows: xq covers x[8g .. 8g+11]; xf = 2 in-flight quads/chain
  float xq0[12], xq1[12];
  f32x4 xfA0, xfB0, xfA1, xfB1;
  *(f32x4*)&xq0[0] = *(const f32x4*)(xr0 + 0);
  *(f32x4*)&xq0[4] = *(const f32x4*)(xr0 + 4);
  *(f32x4*)&xq0[8] = *(const f32x4*)(xr0 + 8);
  *(f32x4*)&xq1[0] = *(const f32x4*)(xr1 + 0);
  *(f32x4*)&xq1[4] = *(const f32x4*)(xr1 + 4);
  *(f32x4*)&xq1[8] = *(const f32x4*)(xr1 + 8);

  // 97 groups of 8 steps (n = 0..775); frag rotation period 4 | 8
  for (int g = 0; g < 97; ++g) {
    if (g > 0) {  // consume quads issued during group g-1
#pragma unroll
      for (int i = 0; i < 4; ++i) {
        xq0[i] = xq0[8 + i];
        xq1[i] = xq1[8 + i];
      }
      *(f32x4*)&xq0[4] = xfA0;
      *(f32x4*)&xq0[8] = xfB0;
      *(f32x4*)&xq1[4] = xfA1;
      *(f32x4*)&xq1[8] = xfB1;
    }
    // issue next group's quads BEFORE this group's frag loads (in-order
    // vmcnt: their wait never drains the frag queue)
    {
      int xo = (g < 96) ? 8 * g + 12 : 780;
      int xo2 = (g < 96) ? 8 * g + 16 : 780;  // g=96: dup-guard (no OOB)
      xfA0 = *(const f32x4*)(xr0 + xo);
      xfB0 = *(const f32x4*)(xr0 + xo2);
      xfA1 = *(const f32x4*)(xr1 + xo);
      xfB1 = *(const f32x4*)(xr1 + xo2);
    }

    float rs0 = 1.0f, rs1 = 1.0f;
    if ((g & 7) == 0) {  // rescale every 64 steps, folded into step-0 scalars
      float ss0 = 0.f, ss1 = 0.f;
#pragma unroll
      for (int p = 0; p < 4; ++p) {
        unsigned u0 = (unsigned)B0g0[p], u1 = (unsigned)B1g0[p];
        float a0 = __uint_as_float(u0 << 16);
        float a1 = __uint_as_float(u0 & 0xFFFF0000u);
        float d0 = __uint_as_float(u1 << 16);
        float d1 = __uint_as_float(u1 & 0xFFFF0000u);
        ss0 += a0 * a0 + a1 * a1 + d0 * d0 + d1 * d1;
        unsigned v0 = (unsigned)B0g1[p], v1 = (unsigned)B1g1[p];
        float e0 = __uint_as_float(v0 << 16);
        float e1 = __uint_as_float(v0 & 0xFFFF0000u);
        float f0 = __uint_as_float(v1 << 16);
        float f1 = __uint_as_float(v1 & 0xFFFF0000u);
        ss1 += e0 * e0 + e1 * e1 + f0 * f0 + f1 * f1;
      }
      ss0 += __shfl_xor(ss0, 16);
      ss0 += __shfl_xor(ss0, 32);
      ss1 += __shfl_xor(ss1, 16);
      ss1 += __shfl_xor(ss1, 32);
      rs0 = rsqrtf(ss0);
      rs1 = rsqrtf(ss1);
    }

    int n0 = 8 * g;  // n0 % 4 == 0
    STEP2G(n0 + 0, frA, frD, xq0[1], xq1[1], rs0, rs1);
    STEP2G(n0 + 1, frB, frA, xq0[2], xq1[2], 1.0f, 1.0f);
    STEP2G(n0 + 2, frC, frB, xq0[3], xq1[3], 1.0f, 1.0f);
    STEP2G(n0 + 3, frD, frC, xq0[4], xq1[4], 1.0f, 1.0f);
    STEP2G(n0 + 4, frA, frD, xq0[5], xq1[5], 1.0f, 1.0f);
    STEP2G(n0 + 5, frB, frA, xq0[6], xq1[6], 1.0f, 1.0f);
    STEP2G(n0 + 6, frC, frB, xq0[7], xq1[7], 1.0f, 1.0f);
    STEP2G(n0 + 7, frD, frC, xq0[8], xq1[8], 1.0f, 1.0f);
  }

  // tail: shift once more (xf from g=96 = quad 780); steps 776..781
  {
#pragma unroll
    for (int i = 0; i < 4; ++i) {
      xq0[i] = xq0[8 + i];
      xq1[i] = xq1[8 + i];
    }
    *(f32x4*)&xq0[4] = xfA0;
    *(f32x4*)&xq1[4] = xfA1;
    STEP2G(776, frA, frD, xq0[1], xq1[1], 1.0f, 1.0f);
    STEP2G(777, frB, frA, xq0[2], xq1[2], 1.0f, 1.0f);
    STEP2G(778, frC, frB, xq0[3], xq1[3], 1.0f, 1.0f);
    STEP2G(779, frD, frC, xq0[4], xq1[4], 1.0f, 1.0f);
    STEP2G(780, frA, frD, xq0[5], xq1[5], 1.0f, 1.0f);
    STEP2G(781, frB, frA, xq0[6], xq1[6], 1.0f, 1.0f);
  }

  // final f32 exchange (unique per (wv,lane)); then normalize + logits, x2
  asm volatile("s_waitcnt lgkmcnt(0)" ::: "memory");
  __builtin_amdgcn_s_barrier();  // all step reads retired
  *(f32x4*)(xlds + wv * 1152 + lane * 16) = own0;
  *(f32x4*)(xlds + 4608 + wv * 1152 + lane * 16) = own1;
  asm volatile("s_waitcnt lgkmcnt(0)" ::: "memory");
  __builtin_amdgcn_s_barrier();
  __builtin_amdgcn_sched_barrier(0);

#pragma unroll
  for (int grp = 0; grp < 2; ++grp) {
    float fm[16];
#pragma unroll
    for (int t = 0; t < 4; ++t) {
      f32x4 v = *(const f32x4*)(xlds + grp * 4608 + t * 1152 + lane * 16);
#pragma unroll
      for (int r = 0; r < 4; ++r) fm[t * 4 + r] = v[r];
    }
    float ss = 0.f;
#pragma unroll
    for (int i = 0; i < 16; ++i) ss += fm[i] * fm[i];
    ss += __shfl_xor(ss, 16);
    ss += __shfl_xor(ss, 32);
    float inv = 1.0f / (sqrtf(ss) + 1e-8f);
#pragma unroll
    for (int i = 0; i < 16; ++i) fm[i] *= inv;

    float xv = grp == 0 ? xq0[7] : xq1[7];  // x[783]
    float s, c;
    __sincosf(PI_2 * xv, &s, &c);
    float part[10];
#pragma unroll
    for (int cc = 0; cc < 10; ++cc) part[cc] = 0.f;
#pragma unroll
    for (int t = 0; t < 4; ++t)
#pragma unroll
      for (int r = 0; r < 4; ++r) {
        int i = 16 * t + 4 * h + r;
        float mv = fm[t * 4 + r];
#pragma unroll
        for (int cc = 0; cc < 10; ++cc)
          part[cc] +=
              mv * (c * core_last[i * 10 + cc] + s * core_last[640 + i * 10 + cc]);
      }
#pragma unroll
    for (int cc = 0; cc < 10; ++cc) {
      part[cc] += __shfl_xor(part[cc], 16);
      part[cc] += __shfl_xor(part[cc], 32);
    }
    if (wv == 0 && h == 0) {
      int brow = grp == 0 ? b0 : b1;
#pragma unroll
      for (int cc = 0; cc < 10; ++cc) out[brow * 10 + cc] = part[cc];
    }
  }
}

// ---- fallback (only if d_ws too small): slow but correct scalar path
__global__ __launch_bounds__(64) void mps_slow(const float* __restrict__ x,
                                               const float* __restrict__ core0,
                                               const float* __restrict__ cm,
                                               const float* __restrict__ cl,
                                               float* __restrict__ out) {
  int b = blockIdx.x * 64 + threadIdx.x;
  float m[64], mn[64];
  float s, c;
  __sincosf(PI_2 * x[(size_t)b * 784], &s, &c);
  for (int d = 0; d < 64; ++d) m[d] = c * core0[d] + s * core0[64 + d];
  for (int n = 0; n < NMID; ++n) {
    __sincosf(PI_2 * x[(size_t)b * 784 + n + 1], &s, &c);
    const float* A0 = cm + (size_t)n * 8192;
    const float* A1 = A0 + 4096;
    for (int j = 0; j < 64; ++j) mn[j] = 0.f;
    for (int i = 0; i < 64; ++i) {
      float w0 = c * m[i], w1 = s * m[i];
      for (int j = 0; j < 64; ++j) mn[j] += w0 * A0[i * 64 + j] + w1 * A1[i * 64 + j];
    }
    float ssn = 0.f;
    for (int j = 0; j < 64; ++j) ssn += mn[j] * mn[j];
    float inv = 1.f / (sqrtf(ssn) + 1e-8f);
    for (int j = 0; j < 64; ++j) m[j] = mn[j] * inv;
  }
  __sincosf(PI_2 * x[(size_t)b * 784 + 783], &s, &c);
  for (int cc = 0; cc < 10; ++cc) {
    float acc = 0.f;
    for (int i = 0; i < 64; ++i)
      acc += m[i] * (c * cl[i * 10 + cc] + s * cl[640 + i * 10 + cc]);
    out[b * 10 + cc] = acc;
  }
}

extern "C" void kernel_launch(void* const* d_in, const int* in_sizes, int n_in,
                              void* d_out, int out_size, void* d_ws, size_t ws_size,
                              hipStream_t stream) {
  const float* x = (const float*)d_in[0];
  const float* core0 = (const float*)d_in[1];
  const float* cm = (const float*)d_in[2];
  const float* cl = (const float*)d_in[3];
  float* out = (float*)d_out;
  size_t need = EG_ELEMS * sizeof(unsigned short);
  if (ws_size >= need) {
    unsigned short* eg = (unsigned short*)d_ws;
    prep_eg<<<NMID, 256, 0, stream>>>(cm, eg);
    mps_main<<<256, 256, 0, stream>>>(x, core0, cl, eg, out);
  } else {
    mps_slow<<<8192 / 64, 64, 0, stream>>>(x, core0, cm, cl, out);
  }
}